// Round 6
// baseline (4260.014 us; speedup 1.0000x reference)
//
#include <hip/hip_runtime.h>

#define N_VOX 200000
#define K_OFF 27
#define P_PAIR 400000
#define C_IN 32
#define C_MID 64
#define C_OUT 32
#define VT 16
#define NGRP (N_VOX / VT)                 // 12500
#define NBUCK (NGRP * K_OFF)              // 337500  (bucket id = group*27 + k)
#define NPAIR_TOT (K_OFF * P_PAIR)        // 10,800,000
#define GPT 49                            // groups per scan thread (49*256 >= 12500)
// tile entry bits: vin[0:18) | local[18:22) | k[22:27) | valid[27]

typedef __attribute__((ext_vector_type(8))) short short8;
typedef __attribute__((ext_vector_type(4))) float f32x4;

__device__ inline short f2bf(float f) {
    union { float f; unsigned u; } v; v.f = f;
    unsigned r = v.u + 0x7FFF + ((v.u >> 16) & 1);   // RNE
    return (short)(r >> 16);
}

// ---------- feats f32 -> bf16 ----------
__global__ __launch_bounds__(256) void cvt_feats(
    const float* __restrict__ in, unsigned short* __restrict__ out)
{
    const int i = blockIdx.x * 256 + threadIdx.x;    // 4 elems each, grid exact
    f32x4 v = ((const f32x4*)in)[i];
    ((unsigned int*)out)[2*i]   = (unsigned short)f2bf(v[0]) | ((unsigned)(unsigned short)f2bf(v[1]) << 16);
    ((unsigned int*)out)[2*i+1] = (unsigned short)f2bf(v[2]) | ((unsigned)(unsigned short)f2bf(v[3]) << 16);
}

// ---------- W -> fragment-ordered bf16 tables ----------
// Wb1[(k*4+nt)*64+lane] : b[j]=W_in[k][(g*8+j)][nt*16+r]
// Wb2[(k*4+nt*2+ks)*64+lane] : b[j]=W_out[k][(ks*32+g*8+j)][nt*16+r]
__global__ __launch_bounds__(64) void cvt_w(
    const float* __restrict__ W_in, const float* __restrict__ W_out,
    short* __restrict__ Wb1, short* __restrict__ Wb2)
{
    const int b = blockIdx.x, lane = threadIdx.x;
    const int g = lane >> 4, r = lane & 15;
    short8 o;
    if (b < 108) {                                   // conv1: k=b/4, nt=b%4
        const int k = b >> 2, nt = b & 3;
        const float* Wk = W_in + (size_t)k * (C_IN * C_MID);
#pragma unroll
        for (int j = 0; j < 8; ++j) o[j] = f2bf(Wk[(g*8+j)*C_MID + nt*16 + r]);
        *(short8*)(Wb1 + (size_t)(b * 64 + lane) * 8) = o;
    } else {                                         // conv2: q = nt*2+ks
        const int b2 = b - 108, k = b2 >> 2, q = b2 & 3;
        const int nt = q >> 1, ks = q & 1;
        const float* Wk = W_out + (size_t)k * (C_MID * C_OUT);
#pragma unroll
        for (int j = 0; j < 8; ++j) o[j] = f2bf(Wk[(ks*32 + g*8 + j)*C_OUT + nt*16 + r]);
        *(short8*)(Wb2 + (size_t)(b2 * 64 + lane) * 8) = o;
    }
}

// ---------- CSR build ----------
__global__ __launch_bounds__(256) void count_kernel(
    const int* __restrict__ out_idx, const float* __restrict__ mask,
    int* __restrict__ counts)
{
    const int e = blockIdx.x * 256 + threadIdx.x;
    if (e >= NPAIR_TOT) return;
    if (mask[e] > 0.5f) {
        const int k = e / P_PAIR;
        atomicAdd(&counts[(out_idx[e] >> 4) * K_OFF + k], 1);
    }
}

// Serial-span scan in GROUP-MAJOR bucket order; capacities rounded to 16 so
// every bucket's entry range is tile-aligned and each group's tiles are
// contiguous. off has NBUCK+1 entries (sentinel).
__global__ __launch_bounds__(256) void scan_kernel(
    const int* __restrict__ counts, int* __restrict__ off,
    int* __restrict__ cursor)
{
    __shared__ int part[256];
    const int t = threadIdx.x;
    const int SPAN = GPT * K_OFF;                    // 1323 buckets, group-aligned
    int s = 0;
    for (int j = 0; j < SPAN; ++j) {
        const int i = t * SPAN + j;
        if (i < NBUCK) s += (counts[i] + 15) & ~15;
    }
    part[t] = s;
    __syncthreads();
    if (t == 0) {
        int run = 0;
        for (int i = 0; i < 256; ++i) { const int tmp = part[i]; part[i] = run; run += tmp; }
    }
    __syncthreads();
    int run = part[t];
    for (int j = 0; j < SPAN; ++j) {
        const int i = t * SPAN + j;
        if (i < NBUCK) {
            off[i] = run; cursor[i] = run;
            run += (counts[i] + 15) & ~15;
            if (i == NBUCK - 1) off[NBUCK] = run;
        }
    }
}

__global__ __launch_bounds__(256) void fill_kernel(
    const int* __restrict__ in_idx, const int* __restrict__ out_idx,
    const float* __restrict__ mask, int* __restrict__ cursor,
    int* __restrict__ tiles)
{
    const int e = blockIdx.x * 256 + threadIdx.x;
    if (e >= NPAIR_TOT) return;
    if (mask[e] > 0.5f) {
        const int k = e / P_PAIR;
        const int v = out_idx[e];
        const int b = (v >> 4) * K_OFF + k;
        const int pos = atomicAdd(&cursor[b], 1);
        tiles[pos] = in_idx[e] | ((v & 15) << 18) | (k << 22) | (1 << 27);
    }
}

// ---------- conv1: tile-streamed, zero loop-carried deps ----------
__global__ __launch_bounds__(256) void conv1_tile(
    const unsigned short* __restrict__ featsb, const short* __restrict__ Wb1,
    const int* __restrict__ tiles, const int* __restrict__ off,
    unsigned short* __restrict__ h)
{
    __shared__ float hs[4][VT * 68];                 // 17,408 B
    const int tid = threadIdx.x, lane = tid & 63, wave = tid >> 6;
    const int g = lane >> 4, r = lane & 15;
    const int G = blockIdx.x * 4 + wave;
    float* hw = hs[wave];
    for (int i = lane; i < VT * 68; i += 64) hw[i] = 0.f;

    const int t0 = off[G * K_OFF] >> 4;
    const int t1 = off[G * K_OFF + K_OFF] >> 4;      // contiguous per group

    for (int t = t0; t < t1; ++t) {
        const int* rec = tiles + (t << 4);           // sequential 64B stream
        const int e0 = rec[0];                       // tile-uniform k source
        const int k  = (e0 >> 22) & 31;
        const int my = rec[r];                       // this lane's A-row entry

        const short8* wp = (const short8*)Wb1 + (size_t)(k * 4) * 64 + lane;
        const short8 f0 = wp[0], f1 = wp[64], f2 = wp[128], f3 = wp[192];

        const int vin = my & 0x3FFFF;
        short8 a = *(const short8*)(featsb + (size_t)vin * C_IN + g * 8);
        if (!((my >> 27) & 1)) a = (short8){0,0,0,0,0,0,0,0};

        f32x4 acc0 = {}, acc1 = {}, acc2 = {}, acc3 = {};
        acc0 = __builtin_amdgcn_mfma_f32_16x16x32_bf16(a, f0, acc0, 0, 0, 0);
        acc1 = __builtin_amdgcn_mfma_f32_16x16x32_bf16(a, f1, acc1, 0, 0, 0);
        acc2 = __builtin_amdgcn_mfma_f32_16x16x32_bf16(a, f2, acc2, 0, 0, 0);
        acc3 = __builtin_amdgcn_mfma_f32_16x16x32_bf16(a, f3, acc3, 0, 0, 0);

#pragma unroll
        for (int i = 0; i < 4; ++i) {                // C/D row m=4g+i, col r
            const int rm = rec[g * 4 + i];           // L1-hot (same line)
            if ((rm >> 27) & 1) {
                float* hp = &hw[((rm >> 18) & 15) * 68 + r];
                atomicAdd(hp +  0, acc0[i]);
                atomicAdd(hp + 16, acc1[i]);
                atomicAdd(hp + 32, acc2[i]);
                atomicAdd(hp + 48, acc3[i]);
            }
        }
    }

    // writeout rows G*16..+15: ReLU + bf16, coalesced
    unsigned int* hout = (unsigned int*)(h + (size_t)G * VT * C_MID);
    for (int i = lane; i < VT * C_MID / 2; i += 64) {
        const int row = (2 * i) >> 6, col = (2 * i) & 63;
        const unsigned short lo = (unsigned short)f2bf(fmaxf(hw[row * 68 + col],     0.f));
        const unsigned short hi = (unsigned short)f2bf(fmaxf(hw[row * 68 + col + 1], 0.f));
        hout[i] = (unsigned)lo | ((unsigned)hi << 16);
    }
}

// ---------- conv2: same structure, K=64, N=32 ----------
__global__ __launch_bounds__(256) void conv2_tile(
    const unsigned short* __restrict__ hb, const short* __restrict__ Wb2,
    const int* __restrict__ tiles, const int* __restrict__ off,
    float* __restrict__ out)
{
    __shared__ float os[4][VT * 36];                 // 9,216 B
    const int tid = threadIdx.x, lane = tid & 63, wave = tid >> 6;
    const int g = lane >> 4, r = lane & 15;
    const int G = blockIdx.x * 4 + wave;
    float* ow = os[wave];
    for (int i = lane; i < VT * 36; i += 64) ow[i] = 0.f;

    const int t0 = off[G * K_OFF] >> 4;
    const int t1 = off[G * K_OFF + K_OFF] >> 4;

    for (int t = t0; t < t1; ++t) {
        const int* rec = tiles + (t << 4);
        const int e0 = rec[0];
        const int k  = (e0 >> 22) & 31;
        const int my = rec[r];

        const short8* wp = (const short8*)Wb2 + (size_t)(k * 4) * 64 + lane;
        const short8 f00 = wp[0], f01 = wp[64], f10 = wp[128], f11 = wp[192];

        const int vin = my & 0x3FFFF;
        const short8* row = (const short8*)(hb + (size_t)vin * C_MID);
        short8 a0 = row[g], a1 = row[4 + g];
        if (!((my >> 27) & 1)) { a0 = (short8){0,0,0,0,0,0,0,0}; a1 = a0; }

        f32x4 acc0 = {}, acc1 = {};
        acc0 = __builtin_amdgcn_mfma_f32_16x16x32_bf16(a0, f00, acc0, 0, 0, 0);
        acc0 = __builtin_amdgcn_mfma_f32_16x16x32_bf16(a1, f01, acc0, 0, 0, 0);
        acc1 = __builtin_amdgcn_mfma_f32_16x16x32_bf16(a0, f10, acc1, 0, 0, 0);
        acc1 = __builtin_amdgcn_mfma_f32_16x16x32_bf16(a1, f11, acc1, 0, 0, 0);

#pragma unroll
        for (int i = 0; i < 4; ++i) {
            const int rm = rec[g * 4 + i];
            if ((rm >> 27) & 1) {
                float* op = &ow[((rm >> 18) & 15) * 36 + r];
                atomicAdd(op +  0, acc0[i]);
                atomicAdd(op + 16, acc1[i]);
            }
        }
    }

    float* optr = out + (size_t)G * VT * C_OUT;
    for (int i = lane; i < VT * C_OUT; i += 64)
        optr[i] = ow[(i >> 5) * 36 + (i & 31)];
}

// ---------------------------------------------------------------------------
extern "C" void kernel_launch(void* const* d_in, const int* in_sizes, int n_in,
                              void* d_out, int out_size, void* d_ws, size_t ws_size,
                              hipStream_t stream) {
    const float* feats   = (const float*)d_in[0];
    const int*   in_idx  = (const int*)  d_in[1];
    const int*   out_idx = (const int*)  d_in[2];
    const float* mask    = (const float*)d_in[3];
    const float* W_in    = (const float*)d_in[4];
    const float* W_out   = (const float*)d_in[5];
    float* out = (float*)d_out;

    // ws layout (bytes)
    char* ws = (char*)d_ws;
    unsigned short* h      = (unsigned short*)(ws);               // 25,600,000
    unsigned short* featsb = (unsigned short*)(ws + 25600000);    // 12,800,000
    short* Wb1   = (short*)(ws + 38400000);                       //    131,072 (pad)
    short* Wb2   = (short*)(ws + 38531072);                       //    131,072 (pad)
    int*   tiles = (int*)  (ws + 38662144);                       // 63,500,000 (worst case 63.45MB)
    int*   counts= (int*)  (ws + 102162144);                      //  1,350,048 (pad)
    int*   off   = (int*)  (ws + 103512192);                      //  1,350,016
    int*   cursor= (int*)  (ws + 104862208);                      //  1,350,000  -> end ~106.2MB

    hipMemsetAsync(counts, 0, NBUCK * sizeof(int), stream);
    hipMemsetAsync(tiles,  0, 63500000, stream);                  // pad entries -> valid=0

    cvt_feats<<<N_VOX * C_IN / 4 / 256, 256, 0, stream>>>(feats, featsb);
    cvt_w<<<216, 64, 0, stream>>>(W_in, W_out, Wb1, Wb2);

    const int nblk = (NPAIR_TOT + 255) / 256;
    count_kernel<<<nblk, 256, 0, stream>>>(out_idx, mask, counts);
    scan_kernel <<<1,    256, 0, stream>>>(counts, off, cursor);
    fill_kernel <<<nblk, 256, 0, stream>>>(in_idx, out_idx, mask, cursor, tiles);

    conv1_tile<<<NGRP / 4, 256, 0, stream>>>(featsb, Wb1, tiles, off, h);
    conv2_tile<<<NGRP / 4, 256, 0, stream>>>(h, Wb2, tiles, off, out);
}

// Round 7
// 3310.670 us; speedup vs baseline: 1.2868x; 1.2868x over previous
//
#include <hip/hip_runtime.h>

#define N_VOX 200000
#define K_OFF 27
#define P_PAIR 400000
#define C_IN 32
#define C_MID 64
#define C_OUT 32
#define VT 16
#define NGRP (N_VOX / VT)                 // 12500
#define NBUCK (NGRP * K_OFF)              // 337500 (bucket = group*27 + k)
#define NPAIR_TOT (K_OFF * P_PAIR)        // 10,800,000
#define NSB ((NBUCK + 255) / 256)         // 1319 scan blocks
// tile entry bits: vin[0:18) | local[18:22) | k[22:27) | valid[27]

typedef __attribute__((ext_vector_type(8))) short short8;
typedef __attribute__((ext_vector_type(4))) float f32x4;

__device__ inline short f2bf(float f) {
    union { float f; unsigned u; } v; v.f = f;
    unsigned r = v.u + 0x7FFF + ((v.u >> 16) & 1);   // RNE
    return (short)(r >> 16);
}

// ---------- feats f32 -> bf16 ----------
__global__ __launch_bounds__(256) void cvt_feats(
    const float* __restrict__ in, unsigned short* __restrict__ out)
{
    const int i = blockIdx.x * 256 + threadIdx.x;    // 4 elems each, grid exact
    f32x4 v = ((const f32x4*)in)[i];
    ((unsigned int*)out)[2*i]   = (unsigned short)f2bf(v[0]) | ((unsigned)(unsigned short)f2bf(v[1]) << 16);
    ((unsigned int*)out)[2*i+1] = (unsigned short)f2bf(v[2]) | ((unsigned)(unsigned short)f2bf(v[3]) << 16);
}

// ---------- W -> fragment-ordered bf16 tables (R6-proven layout) ----------
__global__ __launch_bounds__(64) void cvt_w(
    const float* __restrict__ W_in, const float* __restrict__ W_out,
    short* __restrict__ Wb1, short* __restrict__ Wb2)
{
    const int b = blockIdx.x, lane = threadIdx.x;
    const int g = lane >> 4, r = lane & 15;
    short8 o;
    if (b < 108) {                                   // conv1: k=b/4, nt=b%4
        const int k = b >> 2, nt = b & 3;
        const float* Wk = W_in + (size_t)k * (C_IN * C_MID);
#pragma unroll
        for (int j = 0; j < 8; ++j) o[j] = f2bf(Wk[(g*8+j)*C_MID + nt*16 + r]);
        *(short8*)(Wb1 + (size_t)(b * 64 + lane) * 8) = o;
    } else {                                         // conv2: q = nt*2+ks
        const int b2 = b - 108, k = b2 >> 2, q = b2 & 3;
        const int nt = q >> 1, ks = q & 1;
        const float* Wk = W_out + (size_t)k * (C_MID * C_OUT);
#pragma unroll
        for (int j = 0; j < 8; ++j) o[j] = f2bf(Wk[(ks*32 + g*8 + j)*C_OUT + nt*16 + r]);
        *(short8*)(Wb2 + (size_t)(b2 * 64 + lane) * 8) = o;
    }
}

// ---------- CSR build ----------
__global__ __launch_bounds__(256) void count_kernel(
    const int* __restrict__ out_idx, const float* __restrict__ mask,
    int* __restrict__ counts)
{
    const int e = blockIdx.x * 256 + threadIdx.x;
    if (e >= NPAIR_TOT) return;
    if (mask[e] > 0.5f) {
        const int k = e / P_PAIR;
        atomicAdd(&counts[(out_idx[e] >> 4) * K_OFF + k], 1);
    }
}

// 3-phase coalesced scan over 16-rounded capacities, group-major order.
__global__ __launch_bounds__(256) void scan_a(
    const int* __restrict__ counts, int* __restrict__ bsum)
{
    __shared__ int s[256];
    const int i = blockIdx.x * 256 + threadIdx.x;
    s[threadIdx.x] = (i < NBUCK) ? ((counts[i] + 15) & ~15) : 0;
    __syncthreads();
    for (int d = 128; d > 0; d >>= 1) {
        if (threadIdx.x < d) s[threadIdx.x] += s[threadIdx.x + d];
        __syncthreads();
    }
    if (threadIdx.x == 0) bsum[blockIdx.x] = s[0];
}

__global__ __launch_bounds__(256) void scan_b(int* __restrict__ bsum)
{
    __shared__ int s[NSB];
    for (int i = threadIdx.x; i < NSB; i += 256) s[i] = bsum[i];
    __syncthreads();
    if (threadIdx.x == 0) {
        int run = 0;
        for (int i = 0; i < NSB; ++i) { const int c = s[i]; s[i] = run; run += c; }
    }
    __syncthreads();
    for (int i = threadIdx.x; i < NSB; i += 256) bsum[i] = s[i];
}

__global__ __launch_bounds__(256) void scan_c(
    const int* __restrict__ counts, const int* __restrict__ bsum,
    int* __restrict__ off, int* __restrict__ cursor)
{
    __shared__ int s[256];
    const int i = blockIdx.x * 256 + threadIdx.x;
    const int c = (i < NBUCK) ? ((counts[i] + 15) & ~15) : 0;
    s[threadIdx.x] = c;
    __syncthreads();
    if (threadIdx.x == 0) {
        int run = bsum[blockIdx.x];
        for (int j = 0; j < 256; ++j) { const int cc = s[j]; s[j] = run; run += cc; }
    }
    __syncthreads();
    if (i < NBUCK) {
        off[i] = s[threadIdx.x]; cursor[i] = s[threadIdx.x];
        if (i == NBUCK - 1) off[NBUCK] = s[threadIdx.x] + c;
    }
}

__global__ __launch_bounds__(256) void fill_kernel(
    const int* __restrict__ in_idx, const int* __restrict__ out_idx,
    const float* __restrict__ mask, int* __restrict__ cursor,
    int* __restrict__ tiles)
{
    const int e = blockIdx.x * 256 + threadIdx.x;
    if (e >= NPAIR_TOT) return;
    if (mask[e] > 0.5f) {
        const int k = e / P_PAIR;
        const int v = out_idx[e];
        const int b = (v >> 4) * K_OFF + k;
        const int pos = atomicAdd(&cursor[b], 1);
        tiles[pos] = in_idx[e] | ((v & 15) << 18) | (k << 22) | (1 << 27);
    }
}

// ---------- conv1: batch-4 tiles -> 64 random lines in flight per wave ----
// Padding entries (0) gather featsb row 0: garbage only corrupts C-row m of
// the SAME entry (MFMA rows independent), and scatter drops invalid rows.
__global__ __launch_bounds__(256, 8) void conv1_tile(
    const unsigned short* __restrict__ featsb, const short* __restrict__ Wb1,
    const int* __restrict__ tiles, const int* __restrict__ off,
    unsigned short* __restrict__ h)
{
    __shared__ float hs[4][VT * 68];                 // 17,408 B
    const int tid = threadIdx.x, lane = tid & 63, wave = tid >> 6;
    const int g = lane >> 4, r = lane & 15;
    const int G = blockIdx.x * 4 + wave;
    float* hw = hs[wave];
    for (int i = lane; i < VT * 68; i += 64) hw[i] = 0.f;

    const int t0 = off[G * K_OFF] >> 4;
    const int t1 = off[G * K_OFF + K_OFF] >> 4;

#define C1_PROC(TT, MY, AV)                                                   \
    {                                                                         \
        const int kk = (__builtin_amdgcn_readfirstlane(MY) >> 22) & 31;       \
        const short8* wp = (const short8*)Wb1 + (size_t)(kk * 4) * 64 + lane; \
        const short8 f0 = wp[0], f1 = wp[64], f2 = wp[128], f3 = wp[192];     \
        f32x4 acc0 = {}, acc1 = {}, acc2 = {}, acc3 = {};                     \
        acc0 = __builtin_amdgcn_mfma_f32_16x16x32_bf16(AV, f0, acc0, 0,0,0);  \
        acc1 = __builtin_amdgcn_mfma_f32_16x16x32_bf16(AV, f1, acc1, 0,0,0);  \
        acc2 = __builtin_amdgcn_mfma_f32_16x16x32_bf16(AV, f2, acc2, 0,0,0);  \
        acc3 = __builtin_amdgcn_mfma_f32_16x16x32_bf16(AV, f3, acc3, 0,0,0);  \
        const int* rec = tiles + ((size_t)(TT) << 4);                         \
        _Pragma("unroll")                                                     \
        for (int i = 0; i < 4; ++i) {                                         \
            const int rm = rec[g * 4 + i];                                    \
            if ((rm >> 27) & 1) {                                             \
                float* hp = &hw[((rm >> 18) & 15) * 68 + r];                  \
                atomicAdd(hp +  0, acc0[i]);                                  \
                atomicAdd(hp + 16, acc1[i]);                                  \
                atomicAdd(hp + 32, acc2[i]);                                  \
                atomicAdd(hp + 48, acc3[i]);                                  \
            }                                                                 \
        }                                                                     \
    }

    int t = t0;
    for (; t + 4 <= t1; t += 4) {
        int my[4];
#pragma unroll
        for (int b = 0; b < 4; ++b) my[b] = tiles[((size_t)(t + b) << 4) | r];
        short8 av[4];
#pragma unroll
        for (int b = 0; b < 4; ++b)
            av[b] = *(const short8*)(featsb + (size_t)(my[b] & 0x3FFFF) * C_IN + g * 8);
        C1_PROC(t + 0, my[0], av[0]);
        C1_PROC(t + 1, my[1], av[1]);
        C1_PROC(t + 2, my[2], av[2]);
        C1_PROC(t + 3, my[3], av[3]);
    }
    for (; t < t1; ++t) {
        const int my0 = tiles[((size_t)t << 4) | r];
        const short8 a0 = *(const short8*)(featsb + (size_t)(my0 & 0x3FFFF) * C_IN + g * 8);
        C1_PROC(t, my0, a0);
    }
#undef C1_PROC

    unsigned int* hout = (unsigned int*)(h + (size_t)G * VT * C_MID);
    for (int i = lane; i < VT * C_MID / 2; i += 64) {
        const int row = (2 * i) >> 6, col = (2 * i) & 63;
        const unsigned short lo = (unsigned short)f2bf(fmaxf(hw[row * 68 + col],     0.f));
        const unsigned short hi = (unsigned short)f2bf(fmaxf(hw[row * 68 + col + 1], 0.f));
        hout[i] = (unsigned)lo | ((unsigned)hi << 16);
    }
}

// ---------- conv2: batch-2 tiles (2 lines/lane each) ----------
__global__ __launch_bounds__(256, 8) void conv2_tile(
    const unsigned short* __restrict__ hb, const short* __restrict__ Wb2,
    const int* __restrict__ tiles, const int* __restrict__ off,
    float* __restrict__ out)
{
    __shared__ float os[4][VT * 36];                 // 9,216 B
    const int tid = threadIdx.x, lane = tid & 63, wave = tid >> 6;
    const int g = lane >> 4, r = lane & 15;
    const int G = blockIdx.x * 4 + wave;
    float* ow = os[wave];
    for (int i = lane; i < VT * 36; i += 64) ow[i] = 0.f;

    const int t0 = off[G * K_OFF] >> 4;
    const int t1 = off[G * K_OFF + K_OFF] >> 4;

#define C2_PROC(TT, MY, A0, A1)                                               \
    {                                                                         \
        const int kk = (__builtin_amdgcn_readfirstlane(MY) >> 22) & 31;       \
        const short8* wp = (const short8*)Wb2 + (size_t)(kk * 4) * 64 + lane; \
        const short8 f00 = wp[0], f01 = wp[64], f10 = wp[128], f11 = wp[192]; \
        f32x4 acc0 = {}, acc1 = {};                                           \
        acc0 = __builtin_amdgcn_mfma_f32_16x16x32_bf16(A0, f00, acc0, 0,0,0); \
        acc0 = __builtin_amdgcn_mfma_f32_16x16x32_bf16(A1, f01, acc0, 0,0,0); \
        acc1 = __builtin_amdgcn_mfma_f32_16x16x32_bf16(A0, f10, acc1, 0,0,0); \
        acc1 = __builtin_amdgcn_mfma_f32_16x16x32_bf16(A1, f11, acc1, 0,0,0); \
        const int* rec = tiles + ((size_t)(TT) << 4);                         \
        _Pragma("unroll")                                                     \
        for (int i = 0; i < 4; ++i) {                                         \
            const int rm = rec[g * 4 + i];                                    \
            if ((rm >> 27) & 1) {                                             \
                float* op = &ow[((rm >> 18) & 15) * 36 + r];                  \
                atomicAdd(op +  0, acc0[i]);                                  \
                atomicAdd(op + 16, acc1[i]);                                  \
            }                                                                 \
        }                                                                     \
    }

    int t = t0;
    for (; t + 2 <= t1; t += 2) {
        int my[2];
#pragma unroll
        for (int b = 0; b < 2; ++b) my[b] = tiles[((size_t)(t + b) << 4) | r];
        short8 a0[2], a1[2];
#pragma unroll
        for (int b = 0; b < 2; ++b) {
            const short8* row = (const short8*)(hb + (size_t)(my[b] & 0x3FFFF) * C_MID);
            a0[b] = row[g]; a1[b] = row[4 + g];
        }
        C2_PROC(t + 0, my[0], a0[0], a1[0]);
        C2_PROC(t + 1, my[1], a0[1], a1[1]);
    }
    for (; t < t1; ++t) {
        const int my0 = tiles[((size_t)t << 4) | r];
        const short8* row = (const short8*)(hb + (size_t)(my0 & 0x3FFFF) * C_MID);
        const short8 x0 = row[g], x1 = row[4 + g];
        C2_PROC(t, my0, x0, x1);
    }
#undef C2_PROC

    float* optr = out + (size_t)G * VT * C_OUT;
    for (int i = lane; i < VT * C_OUT; i += 64)
        optr[i] = ow[(i >> 5) * 36 + (i & 31)];
}

// ---------------------------------------------------------------------------
extern "C" void kernel_launch(void* const* d_in, const int* in_sizes, int n_in,
                              void* d_out, int out_size, void* d_ws, size_t ws_size,
                              hipStream_t stream) {
    const float* feats   = (const float*)d_in[0];
    const int*   in_idx  = (const int*)  d_in[1];
    const int*   out_idx = (const int*)  d_in[2];
    const float* mask    = (const float*)d_in[3];
    const float* W_in    = (const float*)d_in[4];
    const float* W_out   = (const float*)d_in[5];
    float* out = (float*)d_out;

    // ws layout (bytes)
    char* ws = (char*)d_ws;
    unsigned short* h      = (unsigned short*)(ws);               // 25,600,000
    unsigned short* featsb = (unsigned short*)(ws + 25600000);    // 12,800,000
    short* Wb1   = (short*)(ws + 38400000);                       //    131,072
    short* Wb2   = (short*)(ws + 38531072);                       //    131,072
    int*   tiles = (int*)  (ws + 38662144);                       // 63,500,000
    int*   counts= (int*)  (ws + 102162144);                      //  1,350,048
    int*   off   = (int*)  (ws + 103512192);                      //  1,350,016
    int*   cursor= (int*)  (ws + 104862208);                      //  1,350,000
    int*   bsum  = (int*)  (ws + 106212208);                      //      5,276 -> ~106.22 MB

    hipMemsetAsync(counts, 0, NBUCK * sizeof(int), stream);
    hipMemsetAsync(tiles,  0, 63500000, stream);                  // padding -> valid=0

    cvt_feats<<<N_VOX * C_IN / 4 / 256, 256, 0, stream>>>(feats, featsb);
    cvt_w<<<216, 64, 0, stream>>>(W_in, W_out, Wb1, Wb2);

    const int nblk = (NPAIR_TOT + 255) / 256;
    count_kernel<<<nblk, 256, 0, stream>>>(out_idx, mask, counts);
    scan_a<<<NSB, 256, 0, stream>>>(counts, bsum);
    scan_b<<<1,   256, 0, stream>>>(bsum);
    scan_c<<<NSB, 256, 0, stream>>>(counts, bsum, off, cursor);
    fill_kernel<<<nblk, 256, 0, stream>>>(in_idx, out_idx, mask, cursor, tiles);

    conv1_tile<<<NGRP / 4, 256, 0, stream>>>(featsb, Wb1, tiles, off, h);
    conv2_tile<<<NGRP / 4, 256, 0, stream>>>(h, Wb2, tiles, off, out);
}

// Round 8
// 3174.540 us; speedup vs baseline: 1.3419x; 1.0429x over previous
//
#include <hip/hip_runtime.h>

#define N_VOX 200000
#define K_OFF 27
#define P_PAIR 400000
#define C_IN 32
#define C_MID 64
#define C_OUT 32
#define VT 16
#define NGRP (N_VOX / VT)                 // 12500
#define NBUCK (NGRP * K_OFF)              // 337500 (bucket = group*27 + k)
#define NPAIR_TOT (K_OFF * P_PAIR)        // 10,800,000
#define NSB ((NBUCK + 255) / 256)         // 1319 scan blocks
// tile entry bits: vin[0:18) | local[18:22) | k[22:27) | valid[27]

typedef __attribute__((ext_vector_type(8))) short short8;
typedef __attribute__((ext_vector_type(4))) float f32x4;

__device__ inline short f2bf(float f) {
    union { float f; unsigned u; } v; v.f = f;
    unsigned r = v.u + 0x7FFF + ((v.u >> 16) & 1);   // RNE
    return (short)(r >> 16);
}

// ---------- feats f32 -> bf16 ----------
__global__ __launch_bounds__(256) void cvt_feats(
    const float* __restrict__ in, unsigned short* __restrict__ out)
{
    const int i = blockIdx.x * 256 + threadIdx.x;
    f32x4 v = ((const f32x4*)in)[i];
    ((unsigned int*)out)[2*i]   = (unsigned short)f2bf(v[0]) | ((unsigned)(unsigned short)f2bf(v[1]) << 16);
    ((unsigned int*)out)[2*i+1] = (unsigned short)f2bf(v[2]) | ((unsigned)(unsigned short)f2bf(v[3]) << 16);
}

// ---------- W -> fragment-ordered bf16 tables ----------
__global__ __launch_bounds__(64) void cvt_w(
    const float* __restrict__ W_in, const float* __restrict__ W_out,
    short* __restrict__ Wb1, short* __restrict__ Wb2)
{
    const int b = blockIdx.x, lane = threadIdx.x;
    const int g = lane >> 4, r = lane & 15;
    short8 o;
    if (b < 108) {                                   // conv1: k=b/4, nt=b%4
        const int k = b >> 2, nt = b & 3;
        const float* Wk = W_in + (size_t)k * (C_IN * C_MID);
#pragma unroll
        for (int j = 0; j < 8; ++j) o[j] = f2bf(Wk[(g*8+j)*C_MID + nt*16 + r]);
        *(short8*)(Wb1 + (size_t)(b * 64 + lane) * 8) = o;
    } else {                                         // conv2: q = nt*2+ks
        const int b2 = b - 108, k = b2 >> 2, q = b2 & 3;
        const int nt = q >> 1, ks = q & 1;
        const float* Wk = W_out + (size_t)k * (C_MID * C_OUT);
#pragma unroll
        for (int j = 0; j < 8; ++j) o[j] = f2bf(Wk[(ks*32 + g*8 + j)*C_OUT + nt*16 + r]);
        *(short8*)(Wb2 + (size_t)(b2 * 64 + lane) * 8) = o;
    }
}

// ---------- CSR build ----------
__global__ __launch_bounds__(256) void count_kernel(
    const int* __restrict__ out_idx, const float* __restrict__ mask,
    int* __restrict__ counts)
{
    const int e = blockIdx.x * 256 + threadIdx.x;
    if (e >= NPAIR_TOT) return;
    if (mask[e] > 0.5f) {
        const int k = e / P_PAIR;
        atomicAdd(&counts[(out_idx[e] >> 4) * K_OFF + k], 1);
    }
}

// 3-phase coalesced scan over 16-rounded capacities, group-major order.
__global__ __launch_bounds__(256) void scan_a(
    const int* __restrict__ counts, int* __restrict__ bsum)
{
    __shared__ int s[256];
    const int i = blockIdx.x * 256 + threadIdx.x;
    s[threadIdx.x] = (i < NBUCK) ? ((counts[i] + 15) & ~15) : 0;
    __syncthreads();
    for (int d = 128; d > 0; d >>= 1) {
        if (threadIdx.x < d) s[threadIdx.x] += s[threadIdx.x + d];
        __syncthreads();
    }
    if (threadIdx.x == 0) bsum[blockIdx.x] = s[0];
}

__global__ __launch_bounds__(256) void scan_b(int* __restrict__ bsum)
{
    __shared__ int s[NSB];
    for (int i = threadIdx.x; i < NSB; i += 256) s[i] = bsum[i];
    __syncthreads();
    if (threadIdx.x == 0) {
        int run = 0;
        for (int i = 0; i < NSB; ++i) { const int c = s[i]; s[i] = run; run += c; }
    }
    __syncthreads();
    for (int i = threadIdx.x; i < NSB; i += 256) bsum[i] = s[i];
}

__global__ __launch_bounds__(256) void scan_c(
    const int* __restrict__ counts, const int* __restrict__ bsum,
    int* __restrict__ off, int* __restrict__ cursor)
{
    __shared__ int s[256];
    const int i = blockIdx.x * 256 + threadIdx.x;
    const int c = (i < NBUCK) ? ((counts[i] + 15) & ~15) : 0;
    s[threadIdx.x] = c;
    __syncthreads();
    if (threadIdx.x == 0) {
        int run = bsum[blockIdx.x];
        for (int j = 0; j < 256; ++j) { const int cc = s[j]; s[j] = run; run += cc; }
    }
    __syncthreads();
    if (i < NBUCK) {
        off[i] = s[threadIdx.x]; cursor[i] = s[threadIdx.x];
        if (i == NBUCK - 1) off[NBUCK] = s[threadIdx.x] + c;
    }
}

__global__ __launch_bounds__(256) void fill_kernel(
    const int* __restrict__ in_idx, const int* __restrict__ out_idx,
    const float* __restrict__ mask, int* __restrict__ cursor,
    int* __restrict__ tiles)
{
    const int e = blockIdx.x * 256 + threadIdx.x;
    if (e >= NPAIR_TOT) return;
    if (mask[e] > 0.5f) {
        const int k = e / P_PAIR;
        const int v = out_idx[e];
        const int b = (v >> 4) * K_OFF + k;
        const int pos = atomicAdd(&cursor[b], 1);
        tiles[pos] = in_idx[e] | ((v & 15) << 18) | (k << 22) | (1 << 27);
    }
}

// ---------- conv1: one block per group; 4 waves split the tile list --------
// Wave w processes tiles t0+w, t0+w+4, ... into its own LDS slice; block
// reduces the 4 slices at the end. 2-deep pipeline: rec prefetched 2 tiles
// ahead, gather 1 ahead (guards are wave-uniform: same t-range for all lanes).
__global__ __launch_bounds__(256, 4) void conv1_tile(
    const unsigned short* __restrict__ featsb, const short* __restrict__ Wb1,
    const int* __restrict__ tiles, const int* __restrict__ off,
    unsigned short* __restrict__ h)
{
    __shared__ float hs[4][VT * 68];                 // 17,408 B
    const int tid = threadIdx.x, lane = tid & 63, wave = tid >> 6;
    const int g = lane >> 4, r = lane & 15;
    const int G = blockIdx.x;
    float* hw = hs[wave];
    for (int i = lane; i < VT * 68; i += 64) hw[i] = 0.f;

    const int t0 = off[G * K_OFF] >> 4;
    const int t1 = off[G * K_OFF + K_OFF] >> 4;

#define C1_PROC(TT, MY, AV)                                                   \
    {                                                                         \
        const int kk = (__builtin_amdgcn_readfirstlane(MY) >> 22) & 31;       \
        const short8* wp = (const short8*)Wb1 + (size_t)(kk * 4) * 64 + lane; \
        const short8 f0 = wp[0], f1 = wp[64], f2 = wp[128], f3 = wp[192];     \
        f32x4 acc0 = {}, acc1 = {}, acc2 = {}, acc3 = {};                     \
        acc0 = __builtin_amdgcn_mfma_f32_16x16x32_bf16(AV, f0, acc0, 0,0,0);  \
        acc1 = __builtin_amdgcn_mfma_f32_16x16x32_bf16(AV, f1, acc1, 0,0,0);  \
        acc2 = __builtin_amdgcn_mfma_f32_16x16x32_bf16(AV, f2, acc2, 0,0,0);  \
        acc3 = __builtin_amdgcn_mfma_f32_16x16x32_bf16(AV, f3, acc3, 0,0,0);  \
        const int* rec = tiles + ((size_t)(TT) << 4);                         \
        _Pragma("unroll")                                                     \
        for (int i = 0; i < 4; ++i) {                                         \
            const int rm = rec[g * 4 + i];                                    \
            if ((rm >> 27) & 1) {                                             \
                float* hp = &hw[((rm >> 18) & 15) * 68 + r];                  \
                atomicAdd(hp +  0, acc0[i]);                                  \
                atomicAdd(hp + 16, acc1[i]);                                  \
                atomicAdd(hp + 32, acc2[i]);                                  \
                atomicAdd(hp + 48, acc3[i]);                                  \
            }                                                                 \
        }                                                                     \
    }

    int t = t0 + wave;
    int myA = 0, myB = 0;
    short8 avA = {};
    if (t < t1)     myA = tiles[((size_t)t << 4) | r];
    if (t + 4 < t1) myB = tiles[((size_t)(t + 4) << 4) | r];
    if (t < t1)
        avA = *(const short8*)(featsb + (size_t)(myA & 0x3FFFF) * C_IN + g * 8);

    for (; t < t1; t += 4) {
        const int myC = (t + 8 < t1) ? tiles[((size_t)(t + 8) << 4) | r] : 0;
        short8 avB = {};
        if (t + 4 < t1)
            avB = *(const short8*)(featsb + (size_t)(myB & 0x3FFFF) * C_IN + g * 8);
        C1_PROC(t, myA, avA);
        myA = myB; myB = myC; avA = avB;
    }
#undef C1_PROC

    __syncthreads();
    // reduce 4 slices, ReLU, bf16-pack, coalesced write
    unsigned int* hout = (unsigned int*)(h + (size_t)G * VT * C_MID);
    for (int i = tid; i < VT * C_MID / 2; i += 256) {
        const int e0 = 2 * i;
        const int row = e0 >> 6, col = e0 & 63;
        const int i0 = row * 68 + col;
        const float s0 = hs[0][i0]     + hs[1][i0]     + hs[2][i0]     + hs[3][i0];
        const float s1 = hs[0][i0 + 1] + hs[1][i0 + 1] + hs[2][i0 + 1] + hs[3][i0 + 1];
        const unsigned short lo = (unsigned short)f2bf(fmaxf(s0, 0.f));
        const unsigned short hi = (unsigned short)f2bf(fmaxf(s1, 0.f));
        hout[i] = (unsigned)lo | ((unsigned)hi << 16);
    }
}

// ---------- conv2: same k-split structure, K=64 (2 gather lines), N=32 -----
__global__ __launch_bounds__(256, 4) void conv2_tile(
    const unsigned short* __restrict__ hb, const short* __restrict__ Wb2,
    const int* __restrict__ tiles, const int* __restrict__ off,
    float* __restrict__ out)
{
    __shared__ float os[4][VT * 36];                 // 9,216 B
    const int tid = threadIdx.x, lane = tid & 63, wave = tid >> 6;
    const int g = lane >> 4, r = lane & 15;
    const int G = blockIdx.x;
    float* ow = os[wave];
    for (int i = lane; i < VT * 36; i += 64) ow[i] = 0.f;

    const int t0 = off[G * K_OFF] >> 4;
    const int t1 = off[G * K_OFF + K_OFF] >> 4;

#define C2_PROC(TT, MY, A0, A1)                                               \
    {                                                                         \
        const int kk = (__builtin_amdgcn_readfirstlane(MY) >> 22) & 31;       \
        const short8* wp = (const short8*)Wb2 + (size_t)(kk * 4) * 64 + lane; \
        const short8 f00 = wp[0], f01 = wp[64], f10 = wp[128], f11 = wp[192]; \
        f32x4 acc0 = {}, acc1 = {};                                           \
        acc0 = __builtin_amdgcn_mfma_f32_16x16x32_bf16(A0, f00, acc0, 0,0,0); \
        acc0 = __builtin_amdgcn_mfma_f32_16x16x32_bf16(A1, f01, acc0, 0,0,0); \
        acc1 = __builtin_amdgcn_mfma_f32_16x16x32_bf16(A0, f10, acc1, 0,0,0); \
        acc1 = __builtin_amdgcn_mfma_f32_16x16x32_bf16(A1, f11, acc1, 0,0,0); \
        const int* rec = tiles + ((size_t)(TT) << 4);                         \
        _Pragma("unroll")                                                     \
        for (int i = 0; i < 4; ++i) {                                         \
            const int rm = rec[g * 4 + i];                                    \
            if ((rm >> 27) & 1) {                                             \
                float* op = &ow[((rm >> 18) & 15) * 36 + r];                  \
                atomicAdd(op +  0, acc0[i]);                                  \
                atomicAdd(op + 16, acc1[i]);                                  \
            }                                                                 \
        }                                                                     \
    }

    int t = t0 + wave;
    int myA = 0, myB = 0;
    short8 a0A = {}, a1A = {};
    if (t < t1)     myA = tiles[((size_t)t << 4) | r];
    if (t + 4 < t1) myB = tiles[((size_t)(t + 4) << 4) | r];
    if (t < t1) {
        const short8* row = (const short8*)(hb + (size_t)(myA & 0x3FFFF) * C_MID);
        a0A = row[g]; a1A = row[4 + g];
    }

    for (; t < t1; t += 4) {
        const int myC = (t + 8 < t1) ? tiles[((size_t)(t + 8) << 4) | r] : 0;
        short8 a0B = {}, a1B = {};
        if (t + 4 < t1) {
            const short8* row = (const short8*)(hb + (size_t)(myB & 0x3FFFF) * C_MID);
            a0B = row[g]; a1B = row[4 + g];
        }
        C2_PROC(t, myA, a0A, a1A);
        myA = myB; myB = myC; a0A = a0B; a1A = a1B;
    }
#undef C2_PROC

    __syncthreads();
    float* optr = out + (size_t)G * VT * C_OUT;
    for (int i = tid; i < VT * C_OUT; i += 256) {
        const int i0 = (i >> 5) * 36 + (i & 31);
        optr[i] = os[0][i0] + os[1][i0] + os[2][i0] + os[3][i0];
    }
}

// ---------------------------------------------------------------------------
extern "C" void kernel_launch(void* const* d_in, const int* in_sizes, int n_in,
                              void* d_out, int out_size, void* d_ws, size_t ws_size,
                              hipStream_t stream) {
    const float* feats   = (const float*)d_in[0];
    const int*   in_idx  = (const int*)  d_in[1];
    const int*   out_idx = (const int*)  d_in[2];
    const float* mask    = (const float*)d_in[3];
    const float* W_in    = (const float*)d_in[4];
    const float* W_out   = (const float*)d_in[5];
    float* out = (float*)d_out;

    // ws layout (bytes)
    char* ws = (char*)d_ws;
    unsigned short* h      = (unsigned short*)(ws);               // 25,600,000
    unsigned short* featsb = (unsigned short*)(ws + 25600000);    // 12,800,000
    short* Wb1   = (short*)(ws + 38400000);                       //    131,072
    short* Wb2   = (short*)(ws + 38531072);                       //    131,072
    int*   tiles = (int*)  (ws + 38662144);                       // 63,500,000
    int*   counts= (int*)  (ws + 102162144);                      //  1,350,048
    int*   off   = (int*)  (ws + 103512192);                      //  1,350,016
    int*   cursor= (int*)  (ws + 104862208);                      //  1,350,000
    int*   bsum  = (int*)  (ws + 106212208);                      //      5,276

    hipMemsetAsync(counts, 0, NBUCK * sizeof(int), stream);
    hipMemsetAsync(tiles,  0, 63500000, stream);                  // padding -> valid=0

    cvt_feats<<<N_VOX * C_IN / 4 / 256, 256, 0, stream>>>(feats, featsb);
    cvt_w<<<216, 64, 0, stream>>>(W_in, W_out, Wb1, Wb2);

    const int nblk = (NPAIR_TOT + 255) / 256;
    count_kernel<<<nblk, 256, 0, stream>>>(out_idx, mask, counts);
    scan_a<<<NSB, 256, 0, stream>>>(counts, bsum);
    scan_b<<<1,   256, 0, stream>>>(bsum);
    scan_c<<<NSB, 256, 0, stream>>>(counts, bsum, off, cursor);
    fill_kernel<<<nblk, 256, 0, stream>>>(in_idx, out_idx, mask, cursor, tiles);

    conv1_tile<<<NGRP, 256, 0, stream>>>(featsb, Wb1, tiles, off, h);
    conv2_tile<<<NGRP, 256, 0, stream>>>(h, Wb2, tiles, off, out);
}